// Round 8
// baseline (1728.621 us; speedup 1.0000x reference)
//
#include <hip/hip_runtime.h>
#include <hip/hip_bf16.h>
#include <cmath>

typedef __hip_bfloat16 bf16;
typedef __attribute__((ext_vector_type(8))) short s16x8;
typedef __attribute__((ext_vector_type(4))) float f32x4v;

__device__ __forceinline__ float bf2f(bf16 v){ return __bfloat162float(v); }
__device__ __forceinline__ bf16  f2bf(float v){ return __float2bfloat16(v); }

__device__ __forceinline__ void gload16(const void* g, void* l){
  __builtin_amdgcn_global_load_lds((const __attribute__((address_space(1))) void*)g,
                                   (__attribute__((address_space(3))) void*)l,
                                   16, 0, 0);
}

// bijective XCD-chunk swizzle (m204)
__device__ __forceinline__ int xcd_swizzle(int bid, int nb){
  int q = nb >> 3, r = nb & 7;
  int xcd = bid & 7, idx = bid >> 3;
  return (xcd < r) ? (xcd*(q+1) + idx) : (r + xcd*q + idx);
}

// tanh-form GELU: v * sigmoid(2*0.79788456*(v + 0.044715 v^3)); |err| ~1e-3
__device__ __forceinline__ float gelu_f(float v){
  float y = 0.797884561f*(v + 0.044715f*v*v*v);
  float e = __expf(-2.f*y);
  return v * __builtin_amdgcn_rcpf(1.f + e);
}

// ---------------- weight fp32 -> bf16 ----------------
__global__ void k_f2bf(const float* __restrict__ in, bf16* __restrict__ out, int n){
  int i = blockIdx.x*256 + threadIdx.x;
  if (i < n) out[i] = f2bf(in[i]);
}

// ------- combined bias+mask table (f32): comb[cls(8)][head(12)][row 128][col 128] -------
__global__ void k_comb(const float* __restrict__ rpb, float* __restrict__ comb){
  int idx = blockIdx.x*256 + threadIdx.x;        // 96*128*128
  int col = idx & 127, row = (idx>>7)&127, clshead = idx>>14;
  int cls = clshead/12, head = clshead - cls*12;
  float v;
  if (row >= 98) v = 0.f;
  else if (col >= 98) v = -10000.f;
  else {
    int qd = row/49, qr = row%49, qh = qr/7, qw = qr%7;
    int kd = col/49, kr = col%49, kh = kr/7, kw = kr%7;
    int pbq = qd*169 + qh*13 + qw;
    int pbk = kd*169 + kh*13 + kw;
    int lq, lk;
    {
      int ld = (cls&4) ? (qd==0?1:2) : 0;
      int lh = (cls&2) ? (qh<4?1:2) : 0;
      int lw = (cls&1) ? (qw<4?1:2) : 0;
      lq = ld*9+lh*3+lw;
    }
    {
      int ld = (cls&4) ? (kd==0?1:2) : 0;
      int lh = (cls&2) ? (kh<4?1:2) : 0;
      int lw = (cls&1) ? (kw<4?1:2) : 0;
      lk = ld*9+lh*3+lw;
    }
    float bias = rpb[(pbq-pbk+253)*12 + head];
    v = bias + ((lq!=lk) ? -100.f : 0.f);
  }
  comb[idx] = v;
}

// ------- LN1 + cyclic shift + window partition (one wave per token) -------
__global__ __launch_bounds__(256)
void k_ln1(const float* __restrict__ x, const float* __restrict__ g,
           const float* __restrict__ b, bf16* __restrict__ xw, long tbase)
{
  int tl = blockIdx.x*4 + (threadIdx.x>>6);
  long t = tbase + tl;
  int lane = threadIdx.x & 63;
  int win = (int)(t / 98), n = (int)(t % 98);
  int batch = win>>8;
  int wq = win & 7, hq = (win>>3)&7, dq = (win>>6)&3;
  int dr = n/49, rem = n%49, hr = rem/7, wr = rem%7;
  int d = dq*2+dr, h = hq*7+hr, w = wq*7+wr;
  int sd = (d+1)&7;
  int sh = h+3; if (sh>=56) sh-=56;
  int sw = w+3; if (sw>=56) sw-=56;
  const float* row = x + ((size_t)(((batch*8+sd)*56+sh)*56+sw))*384;
  float v[6]; float s=0.f, ss=0.f;
  int c0 = lane*6;
  #pragma unroll
  for (int i=0;i<6;++i){ float f = row[c0+i]; v[i]=f; s+=f; ss+=f*f; }
  #pragma unroll
  for (int o=32;o>0;o>>=1){ s += __shfl_xor(s,o); ss += __shfl_xor(ss,o); }
  float mu = s*(1.f/384.f);
  float var = ss*(1.f/384.f) - mu*mu;
  float rstd = rsqrtf(var + 1e-5f);
  bf16* orow = xw + (size_t)tl*384;
  #pragma unroll
  for (int i=0;i<6;++i){ int c=c0+i; orow[c] = f2bf((v[i]-mu)*rstd*g[c] + b[c]); }
}

// ------- scatter (window reverse + roll back) + residual + LN2 -------
__global__ __launch_bounds__(256)
void k_scatter_ln2(const bf16* __restrict__ projout, const float* __restrict__ x,
                   const float* __restrict__ g, const float* __restrict__ b,
                   float* __restrict__ x2, bf16* __restrict__ ln2,
                   long tbase, long lnbase)
{
  int tl = blockIdx.x*4 + (threadIdx.x>>6);
  long t = tbase + tl;
  int lane = threadIdx.x & 63;
  int win = (int)(t/98), n = (int)(t%98);
  int batch = win>>8;
  int wq = win&7, hq=(win>>3)&7, dq=(win>>6)&3;
  int dr=n/49, rem=n%49, hr=rem/7, wr=rem%7;
  int d=dq*2+dr, h=hq*7+hr, w=wq*7+wr;
  int sd=(d+1)&7;
  int sh=h+3; if(sh>=56)sh-=56;
  int sw=w+3; if(sw>=56)sw-=56;
  size_t nat = (size_t)(sd*56+sh)*56 + sw;            // within batch [0,25088)
  size_t nrow = (size_t)batch*25088 + nat;            // global natural row
  const float* xrow = x + nrow*384;
  const bf16* prow = projout + (size_t)tl*384;
  float* x2row = x2 + nrow*384;
  bf16* lrow = ln2 + (nrow - (size_t)lnbase)*384;
  int c0 = lane*6;
  float v[6]; float s=0.f, ss=0.f;
  #pragma unroll
  for (int i=0;i<6;++i){
    float f = xrow[c0+i] + bf2f(prow[c0+i]);
    v[i]=f; s+=f; ss+=f*f;
    x2row[c0+i] = f;
  }
  #pragma unroll
  for (int o=32;o>0;o>>=1){ s+=__shfl_xor(s,o); ss+=__shfl_xor(ss,o); }
  float mu=s*(1.f/384.f), var=ss*(1.f/384.f)-mu*mu, rstd=rsqrtf(var+1e-5f);
  #pragma unroll
  for (int i=0;i<6;++i){ int c=c0+i; lrow[c]=f2bf((v[i]-mu)*rstd*g[c]+b[c]); }
}

// ------- bf16 MFMA GEMM, out[m,n] = sum_k A[m,k]*B[n,k] + bias[n] (both K-major) -------
// Block tile 256x128, 4 waves, per-wave 128x64 (LDS-BW-optimal: 0.023 B/FLOP).
// 3-buffer LDS ring, depth-2 prefetch, counted vmcnt(6) before raw s_barrier,
// chunk-XOR LDS swizzle (0 conflicts measured). MT m-subtiles per block.
// EPI: 0 = bias -> bf16; 1 = bias+GELU -> bf16; 2 = bias+resid -> f32; 3 = bias, scale cols<384 -> bf16
template<int EPI, int KT, int MT>
__global__ __launch_bounds__(256)
void k_gemm(const bf16* __restrict__ A, const bf16* __restrict__ B,
            const float* __restrict__ bias, const float* __restrict__ resid,
            void* __restrict__ outp, int N, int nx)
{
  constexpr int K = KT*32;
  constexpr int TOT = KT*MT;
  __shared__ __align__(16) bf16 As[3][256*32];
  __shared__ __align__(16) bf16 Bs[3][128*32];
  const int tid = threadIdx.x;
  const int wave = tid>>6, lane = tid&63;
  const int wg = xcd_swizzle(blockIdx.x, gridDim.x);
  const int tn = wg % nx, mgrp = wg / nx;
  const int wm = wave>>1, wn = wave&1;      // wave tile 128x64 at (wm*128, wn*64)
  const int fr = lane & 15, l4 = lane>>4;

  f32x4v acc[8][4];
  #pragma unroll
  for (int i=0;i<8;++i)
    #pragma unroll
    for (int j=0;j<4;++j)
      #pragma unroll
      for (int e=0;e<4;++e) acc[i][j][e] = 0.f;

  const int srow0 = lane>>2;
  // pre-swizzled global chunk: LDS[r][c] holds global[r][c ^ ((r>>1)&3)]
  const int scol_sw = (((lane&3) ^ ((lane>>3)&3)))*8;
  const bf16* gA = A + ((size_t)(mgrp*MT)*256 + wave*16 + srow0)*K + scol_sw;
  const bf16* gB = B + ((size_t)tn*128 + wave*16 + srow0)*K + scol_sw;

  auto stage = [&](int buf, int gs){
    int mt = gs/KT, kt = gs - mt*KT;
    const bf16* ga = gA + (size_t)mt*256*K + kt*32;
    const bf16* gb = gB + kt*32;
    bf16* la = &As[buf][wave*16*32];
    bf16* lb = &Bs[buf][wave*16*32];
    #pragma unroll
    for (int j=0;j<4;++j)
      gload16(ga + (size_t)(64*j)*K, la + j*64*32);
    #pragma unroll
    for (int j=0;j<2;++j)
      gload16(gb + (size_t)(64*j)*K, lb + j*64*32);
  };

  stage(0,0); stage(1,1);      // depth-2 prefetch (12 loads/wave in flight)

  // swizzled read chunk (lane-constant)
  const int fko_sw = ((l4 ^ ((fr>>1)&3)))*8;

  int rb = 0, sb = 2;
  for (int gs=0; gs<TOT; ++gs){
    if (gs < TOT-1) asm volatile("s_waitcnt vmcnt(6) lgkmcnt(0)" ::: "memory");
    else            asm volatile("s_waitcnt vmcnt(0) lgkmcnt(0)" ::: "memory");
    __builtin_amdgcn_s_barrier();
    if (gs+2 < TOT) stage(sb, gs+2);
    const bf16* Ab = As[rb];
    const bf16* Bb = Bs[rb];
    s16x8 af[8], bfr[4];
    #pragma unroll
    for (int i=0;i<8;++i)
      af[i]  = *(const s16x8*)&Ab[(wm*128 + i*16 + fr)*32 + fko_sw];
    #pragma unroll
    for (int i=0;i<4;++i)
      bfr[i] = *(const s16x8*)&Bb[(wn*64 + i*16 + fr)*32 + fko_sw];
    #pragma unroll
    for (int mi=0;mi<8;++mi)
      #pragma unroll
      for (int ni=0;ni<4;++ni)
        acc[mi][ni] = __builtin_amdgcn_mfma_f32_16x16x32_bf16(af[mi], bfr[ni], acc[mi][ni], 0,0,0);
    rb = (rb==2) ? 0 : rb+1;
    sb = (sb==2) ? 0 : sb+1;

    if (((gs+1) % KT) == 0){
      // epilogue for subtile mt = gs/KT (stores overlap next subtile's prefetch)
      int tm = mgrp*MT + gs/KT;
      #pragma unroll
      for (int mi=0;mi<8;++mi){
        #pragma unroll
        for (int ni=0;ni<4;++ni){
          int col = tn*128 + wn*64 + ni*16 + fr;
          float bv = bias[col];
          int rowb = tm*256 + wm*128 + mi*16 + l4*4;
          #pragma unroll
          for (int r=0;r<4;++r){
            size_t idx = (size_t)(rowb+r)*N + col;
            float v = acc[mi][ni][r] + bv;
            if (EPI==0){
              ((bf16*)outp)[idx] = f2bf(v);
            } else if (EPI==1){
              ((bf16*)outp)[idx] = f2bf(gelu_f(v));
            } else if (EPI==3){
              if (col < 384) v *= 0.17677669529663687f;
              ((bf16*)outp)[idx] = f2bf(v);
            } else {
              ((float*)outp)[idx] = v + resid[idx];
            }
            acc[mi][ni][r] = 0.f;
          }
        }
      }
    }
  }
}

// ------- MFMA windowed attention: 4 waves per block, one (win, head) per block -------
__global__ __launch_bounds__(256)
void k_attn(const bf16* __restrict__ qkv, const float* __restrict__ comb,
            bf16* __restrict__ outp)
{
  const int wg   = xcd_swizzle(blockIdx.x, gridDim.x);
  const int head = wg % 12;
  const int win  = wg / 12;
  const int tid  = threadIdx.x;
  const int wave = tid>>6;
  const int lane = tid&63;
  const int l15 = lane & 15, l4 = lane>>4;
  __shared__ __align__(16) bf16 Vt[32*136];       // V transposed [d][m], padded stride
  __shared__ __align__(16) bf16 P_buf[4][16*40];  // per-wave P tile, padded stride

  const int wq = win&7, hq=(win>>3)&7, dq=(win>>6)&3;
  const int cls = ((dq==3)?4:0) | ((hq==7)?2:0) | ((wq==7)?1:0);
  const float* combbase = comb + (size_t)(cls*12+head)*128*128;
  const bf16* qkvw_ = qkv + (size_t)win*98*1152;

  // cooperative V-transpose staging
  for (int i = tid; i < 512; i += 256){
    int m = i>>2, d0 = (i&3)*8;
    int mc = m>97 ? 97 : m;
    s16x8 v = *(const s16x8*)(qkvw_ + (size_t)mc*1152 + 768 + head*32 + d0);
    #pragma unroll
    for (int e=0;e<8;++e){ short sv = v[e]; Vt[(d0+e)*136 + m] = *(bf16*)&sv; }
  }
  // K fragments in registers
  s16x8 kb[8];
  #pragma unroll
  for (int j=0;j<8;++j){
    int tok = j*16 + l15; if (tok>97) tok = 97;
    kb[j] = *(const s16x8*)(qkvw_ + (size_t)tok*1152 + 384 + head*32 + l4*8);
  }
  __syncthreads();

  const int c0 = wave*32;          // this wave's 32 query rows
  bf16* Pw = P_buf[wave];
  #pragma unroll
  for (int mi=0;mi<2;++mi){
    int q = c0 + mi*16 + l15; if (q>97) q=97;
    s16x8 aq = *(const s16x8*)(qkvw_ + (size_t)q*1152 + head*32 + l4*8);
    f32x4v s[8];
    const float* cb = combbase + (size_t)(c0+mi*16+l4*4)*128 + l15;
    #pragma unroll
    for (int j=0;j<8;++j){
      f32x4v ci = { cb[j*16], cb[j*16+128], cb[j*16+256], cb[j*16+384] };
      s[j] = __builtin_amdgcn_mfma_f32_16x16x32_bf16(aq, kb[j], ci, 0,0,0);
    }
    float rinv[4];
    #pragma unroll
    for (int r=0;r<4;++r){
      float mx = s[0][r];
      #pragma unroll
      for (int j=1;j<8;++j) mx = fmaxf(mx, s[j][r]);
      mx = fmaxf(mx, __shfl_xor(mx,1));
      mx = fmaxf(mx, __shfl_xor(mx,2));
      mx = fmaxf(mx, __shfl_xor(mx,4));
      mx = fmaxf(mx, __shfl_xor(mx,8));
      float sum = 0.f;
      #pragma unroll
      for (int j=0;j<8;++j){ float e = __expf(s[j][r]-mx); s[j][r]=e; sum+=e; }
      sum += __shfl_xor(sum,1);
      sum += __shfl_xor(sum,2);
      sum += __shfl_xor(sum,4);
      sum += __shfl_xor(sum,8);
      rinv[r] = 1.f/sum;
    }
    f32x4v oacc[2] = {{0.f,0.f,0.f,0.f},{0.f,0.f,0.f,0.f}};
    #pragma unroll
    for (int ks=0; ks<4; ++ks){
      #pragma unroll
      for (int jj=0;jj<2;++jj)
        #pragma unroll
        for (int r=0;r<4;++r)
          Pw[(l4*4+r)*40 + jj*16 + l15] = f2bf(s[ks*2+jj][r]);
      s16x8 pa = *(const s16x8*)&Pw[l15*40 + l4*8];
      #pragma unroll
      for (int ni=0;ni<2;++ni){
        s16x8 vb = *(const s16x8*)&Vt[(ni*16+l15)*136 + ks*32 + l4*8];
        oacc[ni] = __builtin_amdgcn_mfma_f32_16x16x32_bf16(pa, vb, oacc[ni], 0,0,0);
      }
    }
    #pragma unroll
    for (int r=0;r<4;++r){
      int qo = c0 + mi*16 + l4*4 + r;
      if (qo < 98){
        bf16* orow = outp + ((size_t)win*98 + qo)*384 + head*32;
        #pragma unroll
        for (int ni=0;ni<2;++ni)
          orow[ni*16+l15] = f2bf(oacc[ni][r]*rinv[r]);
      }
    }
  }
}

extern "C" void kernel_launch(void* const* d_in, const int* in_sizes, int n_in,
                              void* d_out, int out_size, void* d_ws, size_t ws_size,
                              hipStream_t stream)
{
  const float* x     = (const float*)d_in[0];
  const float* n1g   = (const float*)d_in[1];
  const float* n1b   = (const float*)d_in[2];
  const float* qkvw  = (const float*)d_in[3];
  const float* qkvbv = (const float*)d_in[4];
  const float* rpb   = (const float*)d_in[5];
  const float* projw = (const float*)d_in[6];
  const float* projb = (const float*)d_in[7];
  const float* n2g   = (const float*)d_in[8];
  const float* n2b   = (const float*)d_in[9];
  const float* fc1w  = (const float*)d_in[10];
  const float* fc1b  = (const float*)d_in[11];
  const float* fc2w  = (const float*)d_in[12];
  const float* fc2b  = (const float*)d_in[13];
  float* out = (float*)d_out;

  char* ws = (char*)d_ws;
  size_t off = 0;
  auto alloc = [&](size_t bytes)->char*{
    char* p = ws + off; off += (bytes + 255) & ~(size_t)255; return p;
  };
  bf16*  wqkv  = (bf16*)alloc((size_t)1152*384*2);
  bf16*  wproj = (bf16*)alloc((size_t)384*384*2);
  bf16*  wfc1  = (bf16*)alloc((size_t)1536*384*2);
  bf16*  wfc2  = (bf16*)alloc((size_t)384*1536*2);
  float* comb  = (float*)alloc((size_t)96*128*128*4);

  k_f2bf<<<(1152*384+255)/256,256,0,stream>>>(qkvw, wqkv, 1152*384);
  k_f2bf<<<(384*384+255)/256,256,0,stream>>>(projw, wproj, 384*384);
  k_f2bf<<<(1536*384+255)/256,256,0,stream>>>(fc1w, wfc1, 1536*384);
  k_f2bf<<<(384*1536+255)/256,256,0,stream>>>(fc2w, wfc2, 384*1536);
  k_comb<<<6144,256,0,stream>>>(rpb, comb);

  const size_t fused_need = off + ((size_t)100352*384*2 + 255 & ~(size_t)255)
                                + ((size_t)100352*1536*2 + 255 & ~(size_t)255)
                                + ((size_t)100352*384*2 + 255 & ~(size_t)255);
  if (ws_size >= fused_need){
    // ---- all-batch fused pipeline (12 launches) ----
    bf16* xw   = (bf16*)alloc((size_t)100352*384*2);   // ln1 out; reused as proj out
    bf16* bufA = (bf16*)alloc((size_t)100352*1536*2);  // qkv out (1152 cols) / fc1 out
    bf16* ln2  = (bf16*)alloc((size_t)100352*384*2);
    bf16* attno = bufA + (size_t)100352*1152;          // tail of bufA during attention
    bf16* projo = xw;

    k_ln1<<<25088,256,0,stream>>>(x, n1g, n1b, xw, 0L);
    k_gemm<3,12,2><<<196*9,256,0,stream>>>(xw, wqkv, qkvbv, nullptr, bufA, 1152, 9);
    k_attn<<<12*1024,256,0,stream>>>(bufA, comb, attno);
    k_gemm<0,12,2><<<196*3,256,0,stream>>>(attno, wproj, projb, nullptr, projo, 384, 3);
    k_scatter_ln2<<<25088,256,0,stream>>>(projo, x, n2g, n2b, out, ln2, 0L, 0L);
    k_gemm<1,12,2><<<196*12,256,0,stream>>>(ln2, wfc1, fc1b, nullptr, bufA, 1536, 12);
    k_gemm<2,48,1><<<392*3,256,0,stream>>>(bufA, wfc2, fc2b, out, (void*)out, 384, 3);
  } else {
    // ---- per-batch fallback (M=25088 = 98x256, 98/2=49 m-groups) ----
    bf16* xw   = (bf16*)alloc((size_t)25088*384*2);
    bf16* bufA = (bf16*)alloc((size_t)25088*1536*2);
    bf16* ln2  = (bf16*)alloc((size_t)25088*384*2);
    bf16* attno = bufA + (size_t)25088*1152;
    bf16* projo = xw;
    for (int b=0; b<4; ++b){
      long tbase = (long)b*25088;
      k_ln1<<<6272,256,0,stream>>>(x, n1g, n1b, xw, tbase);
      k_gemm<3,12,2><<<49*9,256,0,stream>>>(xw, wqkv, qkvbv, nullptr, bufA, 1152, 9);
      k_attn<<<12*256,256,0,stream>>>(bufA, comb, attno);
      k_gemm<0,12,2><<<49*3,256,0,stream>>>(attno, wproj, projb, nullptr, projo, 384, 3);
      k_scatter_ln2<<<6272,256,0,stream>>>(projo, x, n2g, n2b, out, ln2, tbase, tbase);
      k_gemm<1,12,2><<<49*12,256,0,stream>>>(ln2, wfc1, fc1b, nullptr, bufA, 1536, 12);
      float* resid = out + (size_t)b*25088*384;
      k_gemm<2,48,1><<<98*3,256,0,stream>>>(bufA, wfc2, fc2b, resid, (void*)resid, 384, 3);
    }
  }
}

// Round 9
// 1035.642 us; speedup vs baseline: 1.6691x; 1.6691x over previous
//
#include <hip/hip_runtime.h>
#include <hip/hip_bf16.h>
#include <cmath>

typedef __hip_bfloat16 bf16;
typedef __attribute__((ext_vector_type(8))) short s16x8;
typedef __attribute__((ext_vector_type(4))) float f32x4v;

__device__ __forceinline__ float bf2f(bf16 v){ return __bfloat162float(v); }
__device__ __forceinline__ bf16  f2bf(float v){ return __float2bfloat16(v); }

__device__ __forceinline__ void gload16(const void* g, void* l){
  __builtin_amdgcn_global_load_lds((const __attribute__((address_space(1))) void*)g,
                                   (__attribute__((address_space(3))) void*)l,
                                   16, 0, 0);
}

// bijective XCD-chunk swizzle (m204)
__device__ __forceinline__ int xcd_swizzle(int bid, int nb){
  int q = nb >> 3, r = nb & 7;
  int xcd = bid & 7, idx = bid >> 3;
  return (xcd < r) ? (xcd*(q+1) + idx) : (r + xcd*q + idx);
}

// tanh-form GELU: v * sigmoid(2*0.79788456*(v + 0.044715 v^3)); |err| ~1e-3
__device__ __forceinline__ float gelu_f(float v){
  float y = 0.797884561f*(v + 0.044715f*v*v*v);
  float e = __expf(-2.f*y);
  return v * __builtin_amdgcn_rcpf(1.f + e);
}

// ---------------- weight fp32 -> bf16 ----------------
__global__ void k_f2bf(const float* __restrict__ in, bf16* __restrict__ out, int n){
  int i = blockIdx.x*256 + threadIdx.x;
  if (i < n) out[i] = f2bf(in[i]);
}

// ------- combined bias+mask table (f32): comb[cls(8)][head(12)][row 128][col 128] -------
__global__ void k_comb(const float* __restrict__ rpb, float* __restrict__ comb){
  int idx = blockIdx.x*256 + threadIdx.x;        // 96*128*128
  int col = idx & 127, row = (idx>>7)&127, clshead = idx>>14;
  int cls = clshead/12, head = clshead - cls*12;
  float v;
  if (row >= 98) v = 0.f;
  else if (col >= 98) v = -10000.f;
  else {
    int qd = row/49, qr = row%49, qh = qr/7, qw = qr%7;
    int kd = col/49, kr = col%49, kh = kr/7, kw = kr%7;
    int pbq = qd*169 + qh*13 + qw;
    int pbk = kd*169 + kh*13 + kw;
    int lq, lk;
    {
      int ld = (cls&4) ? (qd==0?1:2) : 0;
      int lh = (cls&2) ? (qh<4?1:2) : 0;
      int lw = (cls&1) ? (qw<4?1:2) : 0;
      lq = ld*9+lh*3+lw;
    }
    {
      int ld = (cls&4) ? (kd==0?1:2) : 0;
      int lh = (cls&2) ? (kh<4?1:2) : 0;
      int lw = (cls&1) ? (kw<4?1:2) : 0;
      lk = ld*9+lh*3+lw;
    }
    float bias = rpb[(pbq-pbk+253)*12 + head];
    v = bias + ((lq!=lk) ? -100.f : 0.f);
  }
  comb[idx] = v;
}

// ------- LN1 + cyclic shift + window partition (one wave per token) -------
__global__ __launch_bounds__(256)
void k_ln1(const float* __restrict__ x, const float* __restrict__ g,
           const float* __restrict__ b, bf16* __restrict__ xw, long tbase)
{
  int tl = blockIdx.x*4 + (threadIdx.x>>6);
  long t = tbase + tl;
  int lane = threadIdx.x & 63;
  int win = (int)(t / 98), n = (int)(t % 98);
  int batch = win>>8;
  int wq = win & 7, hq = (win>>3)&7, dq = (win>>6)&3;
  int dr = n/49, rem = n%49, hr = rem/7, wr = rem%7;
  int d = dq*2+dr, h = hq*7+hr, w = wq*7+wr;
  int sd = (d+1)&7;
  int sh = h+3; if (sh>=56) sh-=56;
  int sw = w+3; if (sw>=56) sw-=56;
  const float* row = x + ((size_t)(((batch*8+sd)*56+sh)*56+sw))*384;
  float v[6]; float s=0.f, ss=0.f;
  int c0 = lane*6;
  #pragma unroll
  for (int i=0;i<6;++i){ float f = row[c0+i]; v[i]=f; s+=f; ss+=f*f; }
  #pragma unroll
  for (int o=32;o>0;o>>=1){ s += __shfl_xor(s,o); ss += __shfl_xor(ss,o); }
  float mu = s*(1.f/384.f);
  float var = ss*(1.f/384.f) - mu*mu;
  float rstd = rsqrtf(var + 1e-5f);
  bf16* orow = xw + (size_t)tl*384;
  #pragma unroll
  for (int i=0;i<6;++i){ int c=c0+i; orow[c] = f2bf((v[i]-mu)*rstd*g[c] + b[c]); }
}

// ------- scatter (window reverse + roll back) + residual + LN2 -------
__global__ __launch_bounds__(256)
void k_scatter_ln2(const bf16* __restrict__ projout, const float* __restrict__ x,
                   const float* __restrict__ g, const float* __restrict__ b,
                   float* __restrict__ x2, bf16* __restrict__ ln2,
                   long tbase, long lnbase)
{
  int tl = blockIdx.x*4 + (threadIdx.x>>6);
  long t = tbase + tl;
  int lane = threadIdx.x & 63;
  int win = (int)(t/98), n = (int)(t%98);
  int batch = win>>8;
  int wq = win&7, hq=(win>>3)&7, dq=(win>>6)&3;
  int dr=n/49, rem=n%49, hr=rem/7, wr=rem%7;
  int d=dq*2+dr, h=hq*7+hr, w=wq*7+wr;
  int sd=(d+1)&7;
  int sh=h+3; if(sh>=56)sh-=56;
  int sw=w+3; if(sw>=56)sw-=56;
  size_t nat = (size_t)(sd*56+sh)*56 + sw;            // within batch [0,25088)
  size_t nrow = (size_t)batch*25088 + nat;            // global natural row
  const float* xrow = x + nrow*384;
  const bf16* prow = projout + (size_t)tl*384;
  float* x2row = x2 + nrow*384;
  bf16* lrow = ln2 + (nrow - (size_t)lnbase)*384;
  int c0 = lane*6;
  float v[6]; float s=0.f, ss=0.f;
  #pragma unroll
  for (int i=0;i<6;++i){
    float f = xrow[c0+i] + bf2f(prow[c0+i]);
    v[i]=f; s+=f; ss+=f*f;
    x2row[c0+i] = f;
  }
  #pragma unroll
  for (int o=32;o>0;o>>=1){ s+=__shfl_xor(s,o); ss+=__shfl_xor(ss,o); }
  float mu=s*(1.f/384.f), var=ss*(1.f/384.f)-mu*mu, rstd=rsqrtf(var+1e-5f);
  #pragma unroll
  for (int i=0;i<6;++i){ int c=c0+i; lrow[c]=f2bf((v[i]-mu)*rstd*g[c]+b[c]); }
}

// ------- bf16 MFMA GEMM, out[m,n] = sum_k A[m,k]*B[n,k] + bias[n] (both K-major) -------
// R7 structure (proven best) + FULLY UNROLLED K-loop: KT is compile-time, so the
// 3-buffer ring indices rb/sb become constants, every ds_read address is a static
// offset from 3 fixed LDS bases, and gload offsets fold to immediates. This kills
// the per-iteration VALU address arithmetic (R7: VALUBusy 42%).
// Counted vmcnt(4) before raw s_barrier keeps loads in flight across barriers.
// Chunk-XOR LDS swizzle (measured 0 conflicts).
// EPI: 0 = bias -> bf16; 1 = bias+GELU -> bf16; 2 = bias+resid -> f32; 3 = bias, scale cols<384 -> bf16
template<int EPI, int KT>
__global__ __launch_bounds__(256)
void k_gemm(const bf16* __restrict__ A, const bf16* __restrict__ B,
            const float* __restrict__ bias, const float* __restrict__ resid,
            void* __restrict__ outp, int N, int nx)
{
  constexpr int K = KT*32;
  __shared__ __align__(16) bf16 As[3][128*32];
  __shared__ __align__(16) bf16 Bs[3][128*32];
  const int tid = threadIdx.x;
  const int wave = tid>>6, lane = tid&63;
  const int wg = xcd_swizzle(blockIdx.x, gridDim.x);
  const int tn = wg % nx, tm = wg / nx;
  const int wm = wave>>1, wn = wave&1;      // 2x2 waves -> 64x64 per wave
  const int fr = lane & 15, l4 = lane>>4;

  f32x4v acc[4][4];
  #pragma unroll
  for (int i=0;i<4;++i)
    #pragma unroll
    for (int j=0;j<4;++j)
      #pragma unroll
      for (int e=0;e<4;++e) acc[i][j][e] = 0.f;

  const int srow0 = lane>>2;
  // pre-swizzled global chunk: LDS[r][c] holds global[r][c ^ ((r>>1)&3)]
  const int scol_sw = (((lane&3) ^ ((lane>>3)&3)))*8;
  const bf16* ga0 = A + (size_t)(tm*128 +      wave*16 + srow0)*K + scol_sw;
  const bf16* ga1 = A + (size_t)(tm*128 + 64 + wave*16 + srow0)*K + scol_sw;
  const bf16* gb0 = B + (size_t)(tn*128 +      wave*16 + srow0)*K + scol_sw;
  const bf16* gb1 = B + (size_t)(tn*128 + 64 + wave*16 + srow0)*K + scol_sw;

  auto stage = [&](int buf, int kt){
    gload16(ga0 + kt*32, &As[buf][       wave*512]);
    gload16(ga1 + kt*32, &As[buf][2048 + wave*512]);
    gload16(gb0 + kt*32, &Bs[buf][       wave*512]);
    gload16(gb1 + kt*32, &Bs[buf][2048 + wave*512]);
  };

  stage(0,0); stage(1,1);      // depth-2 prefetch (8 loads in flight)

  // swizzled read chunk (lane-constant)
  const int fko_sw = ((l4 ^ ((fr>>1)&3)))*8;

  #pragma unroll
  for (int kt=0; kt<KT; ++kt){
    if (kt < KT-1) asm volatile("s_waitcnt vmcnt(4) lgkmcnt(0)" ::: "memory");
    else           asm volatile("s_waitcnt vmcnt(0) lgkmcnt(0)" ::: "memory");
    __builtin_amdgcn_s_barrier();
    if (kt+2 < KT) stage((kt+2)%3, kt+2);
    const int rb = kt%3;                 // compile-time under full unroll
    const bf16* Ab = As[rb];
    const bf16* Bb = Bs[rb];
    s16x8 af[4], bfr[4];
    #pragma unroll
    for (int i=0;i<4;++i){
      af[i]  = *(const s16x8*)&Ab[(wm*64 + i*16 + fr)*32 + fko_sw];
      bfr[i] = *(const s16x8*)&Bb[(wn*64 + i*16 + fr)*32 + fko_sw];
    }
    #pragma unroll
    for (int mi=0;mi<4;++mi)
      #pragma unroll
      for (int ni=0;ni<4;++ni)
        acc[mi][ni] = __builtin_amdgcn_mfma_f32_16x16x32_bf16(af[mi], bfr[ni], acc[mi][ni], 0,0,0);
  }

  #pragma unroll
  for (int mi=0;mi<4;++mi){
    #pragma unroll
    for (int ni=0;ni<4;++ni){
      int col = tn*128 + wn*64 + ni*16 + fr;
      float bv = bias[col];
      int rowb = tm*128 + wm*64 + mi*16 + l4*4;
      #pragma unroll
      for (int r=0;r<4;++r){
        size_t idx = (size_t)(rowb+r)*N + col;
        float v = acc[mi][ni][r] + bv;
        if (EPI==0){
          ((bf16*)outp)[idx] = f2bf(v);
        } else if (EPI==1){
          ((bf16*)outp)[idx] = f2bf(gelu_f(v));
        } else if (EPI==3){
          if (col < 384) v *= 0.17677669529663687f;
          ((bf16*)outp)[idx] = f2bf(v);
        } else {
          ((float*)outp)[idx] = v + resid[idx];
        }
      }
    }
  }
}

// ------- MFMA windowed attention: 4 waves per block, one (win, head) per block -------
__global__ __launch_bounds__(256)
void k_attn(const bf16* __restrict__ qkv, const float* __restrict__ comb,
            bf16* __restrict__ outp)
{
  const int wg   = xcd_swizzle(blockIdx.x, gridDim.x);
  const int head = wg % 12;
  const int win  = wg / 12;
  const int tid  = threadIdx.x;
  const int wave = tid>>6;
  const int lane = tid&63;
  const int l15 = lane & 15, l4 = lane>>4;
  __shared__ __align__(16) bf16 Vt[32*136];       // V transposed [d][m], padded stride
  __shared__ __align__(16) bf16 P_buf[4][16*40];  // per-wave P tile, padded stride

  const int wq = win&7, hq=(win>>3)&7, dq=(win>>6)&3;
  const int cls = ((dq==3)?4:0) | ((hq==7)?2:0) | ((wq==7)?1:0);
  const float* combbase = comb + (size_t)(cls*12+head)*128*128;
  const bf16* qkvw_ = qkv + (size_t)win*98*1152;

  // cooperative V-transpose staging
  for (int i = tid; i < 512; i += 256){
    int m = i>>2, d0 = (i&3)*8;
    int mc = m>97 ? 97 : m;
    s16x8 v = *(const s16x8*)(qkvw_ + (size_t)mc*1152 + 768 + head*32 + d0);
    #pragma unroll
    for (int e=0;e<8;++e){ short sv = v[e]; Vt[(d0+e)*136 + m] = *(bf16*)&sv; }
  }
  // K fragments in registers
  s16x8 kb[8];
  #pragma unroll
  for (int j=0;j<8;++j){
    int tok = j*16 + l15; if (tok>97) tok = 97;
    kb[j] = *(const s16x8*)(qkvw_ + (size_t)tok*1152 + 384 + head*32 + l4*8);
  }
  __syncthreads();

  const int c0 = wave*32;          // this wave's 32 query rows
  bf16* Pw = P_buf[wave];
  #pragma unroll
  for (int mi=0;mi<2;++mi){
    int q = c0 + mi*16 + l15; if (q>97) q=97;
    s16x8 aq = *(const s16x8*)(qkvw_ + (size_t)q*1152 + head*32 + l4*8);
    f32x4v s[8];
    const float* cb = combbase + (size_t)(c0+mi*16+l4*4)*128 + l15;
    #pragma unroll
    for (int j=0;j<8;++j){
      f32x4v ci = { cb[j*16], cb[j*16+128], cb[j*16+256], cb[j*16+384] };
      s[j] = __builtin_amdgcn_mfma_f32_16x16x32_bf16(aq, kb[j], ci, 0,0,0);
    }
    float rinv[4];
    #pragma unroll
    for (int r=0;r<4;++r){
      float mx = s[0][r];
      #pragma unroll
      for (int j=1;j<8;++j) mx = fmaxf(mx, s[j][r]);
      mx = fmaxf(mx, __shfl_xor(mx,1));
      mx = fmaxf(mx, __shfl_xor(mx,2));
      mx = fmaxf(mx, __shfl_xor(mx,4));
      mx = fmaxf(mx, __shfl_xor(mx,8));
      float sum = 0.f;
      #pragma unroll
      for (int j=0;j<8;++j){ float e = __expf(s[j][r]-mx); s[j][r]=e; sum+=e; }
      sum += __shfl_xor(sum,1);
      sum += __shfl_xor(sum,2);
      sum += __shfl_xor(sum,4);
      sum += __shfl_xor(sum,8);
      rinv[r] = 1.f/sum;
    }
    f32x4v oacc[2] = {{0.f,0.f,0.f,0.f},{0.f,0.f,0.f,0.f}};
    #pragma unroll
    for (int ks=0; ks<4; ++ks){
      #pragma unroll
      for (int jj=0;jj<2;++jj)
        #pragma unroll
        for (int r=0;r<4;++r)
          Pw[(l4*4+r)*40 + jj*16 + l15] = f2bf(s[ks*2+jj][r]);
      s16x8 pa = *(const s16x8*)&Pw[l15*40 + l4*8];
      #pragma unroll
      for (int ni=0;ni<2;++ni){
        s16x8 vb = *(const s16x8*)&Vt[(ni*16+l15)*136 + ks*32 + l4*8];
        oacc[ni] = __builtin_amdgcn_mfma_f32_16x16x32_bf16(pa, vb, oacc[ni], 0,0,0);
      }
    }
    #pragma unroll
    for (int r=0;r<4;++r){
      int qo = c0 + mi*16 + l4*4 + r;
      if (qo < 98){
        bf16* orow = outp + ((size_t)win*98 + qo)*384 + head*32;
        #pragma unroll
        for (int ni=0;ni<2;++ni)
          orow[ni*16+l15] = f2bf(oacc[ni][r]*rinv[r]);
      }
    }
  }
}

extern "C" void kernel_launch(void* const* d_in, const int* in_sizes, int n_in,
                              void* d_out, int out_size, void* d_ws, size_t ws_size,
                              hipStream_t stream)
{
  const float* x     = (const float*)d_in[0];
  const float* n1g   = (const float*)d_in[1];
  const float* n1b   = (const float*)d_in[2];
  const float* qkvw  = (const float*)d_in[3];
  const float* qkvbv = (const float*)d_in[4];
  const float* rpb   = (const float*)d_in[5];
  const float* projw = (const float*)d_in[6];
  const float* projb = (const float*)d_in[7];
  const float* n2g   = (const float*)d_in[8];
  const float* n2b   = (const float*)d_in[9];
  const float* fc1w  = (const float*)d_in[10];
  const float* fc1b  = (const float*)d_in[11];
  const float* fc2w  = (const float*)d_in[12];
  const float* fc2b  = (const float*)d_in[13];
  float* out = (float*)d_out;

  char* ws = (char*)d_ws;
  size_t off = 0;
  auto alloc = [&](size_t bytes)->char*{
    char* p = ws + off; off += (bytes + 255) & ~(size_t)255; return p;
  };
  bf16*  wqkv  = (bf16*)alloc((size_t)1152*384*2);
  bf16*  wproj = (bf16*)alloc((size_t)384*384*2);
  bf16*  wfc1  = (bf16*)alloc((size_t)1536*384*2);
  bf16*  wfc2  = (bf16*)alloc((size_t)384*1536*2);
  float* comb  = (float*)alloc((size_t)96*128*128*4);

  k_f2bf<<<(1152*384+255)/256,256,0,stream>>>(qkvw, wqkv, 1152*384);
  k_f2bf<<<(384*384+255)/256,256,0,stream>>>(projw, wproj, 384*384);
  k_f2bf<<<(1536*384+255)/256,256,0,stream>>>(fc1w, wfc1, 1536*384);
  k_f2bf<<<(384*1536+255)/256,256,0,stream>>>(fc2w, wfc2, 384*1536);
  k_comb<<<6144,256,0,stream>>>(rpb, comb);

  const size_t fused_need = off + ((size_t)100352*384*2 + 255 & ~(size_t)255)
                                + ((size_t)100352*1536*2 + 255 & ~(size_t)255)
                                + ((size_t)100352*384*2 + 255 & ~(size_t)255);
  if (ws_size >= fused_need){
    // ---- all-batch fused pipeline (12 launches) ----
    bf16* xw   = (bf16*)alloc((size_t)100352*384*2);   // ln1 out; reused as proj out
    bf16* bufA = (bf16*)alloc((size_t)100352*1536*2);  // qkv out (1152 cols) / fc1 out
    bf16* ln2  = (bf16*)alloc((size_t)100352*384*2);
    bf16* attno = bufA + (size_t)100352*1152;          // tail of bufA during attention
    bf16* projo = xw;

    k_ln1<<<25088,256,0,stream>>>(x, n1g, n1b, xw, 0L);
    k_gemm<3,12><<<9*784,256,0,stream>>>(xw, wqkv, qkvbv, nullptr, bufA, 1152, 9);
    k_attn<<<12*1024,256,0,stream>>>(bufA, comb, attno);
    k_gemm<0,12><<<3*784,256,0,stream>>>(attno, wproj, projb, nullptr, projo, 384, 3);
    k_scatter_ln2<<<25088,256,0,stream>>>(projo, x, n2g, n2b, out, ln2, 0L, 0L);
    k_gemm<1,12><<<12*784,256,0,stream>>>(ln2, wfc1, fc1b, nullptr, bufA, 1536, 12);
    k_gemm<2,48><<<3*784,256,0,stream>>>(bufA, wfc2, fc2b, out, (void*)out, 384, 3);
  } else {
    // ---- per-batch fallback ----
    bf16* xw   = (bf16*)alloc((size_t)25088*384*2);
    bf16* bufA = (bf16*)alloc((size_t)25088*1536*2);
    bf16* ln2  = (bf16*)alloc((size_t)25088*384*2);
    bf16* attno = bufA + (size_t)25088*1152;
    bf16* projo = xw;
    for (int b=0; b<4; ++b){
      long tbase = (long)b*25088;
      k_ln1<<<6272,256,0,stream>>>(x, n1g, n1b, xw, tbase);
      k_gemm<3,12><<<9*196,256,0,stream>>>(xw, wqkv, qkvbv, nullptr, bufA, 1152, 9);
      k_attn<<<12*256,256,0,stream>>>(bufA, comb, attno);
      k_gemm<0,12><<<3*196,256,0,stream>>>(attno, wproj, projb, nullptr, projo, 384, 3);
      k_scatter_ln2<<<6272,256,0,stream>>>(projo, x, n2g, n2b, out, ln2, tbase, tbase);
      k_gemm<1,12><<<12*196,256,0,stream>>>(ln2, wfc1, fc1b, nullptr, bufA, 1536, 12);
      float* resid = out + (size_t)b*25088*384;
      k_gemm<2,48><<<3*196,256,0,stream>>>(bufA, wfc2, fc2b, resid, (void*)resid, 384, 3);
    }
  }
}

// Round 10
// 983.288 us; speedup vs baseline: 1.7580x; 1.0532x over previous
//
#include <hip/hip_runtime.h>
#include <hip/hip_bf16.h>
#include <cmath>

typedef __hip_bfloat16 bf16;
typedef __attribute__((ext_vector_type(8))) short s16x8;
typedef __attribute__((ext_vector_type(4))) float f32x4v;

__device__ __forceinline__ float bf2f(bf16 v){ return __bfloat162float(v); }
__device__ __forceinline__ bf16  f2bf(float v){ return __float2bfloat16(v); }

__device__ __forceinline__ void gload16(const void* g, void* l){
  __builtin_amdgcn_global_load_lds((const __attribute__((address_space(1))) void*)g,
                                   (__attribute__((address_space(3))) void*)l,
                                   16, 0, 0);
}

// bijective XCD-chunk swizzle (m204)
__device__ __forceinline__ int xcd_swizzle(int bid, int nb){
  int q = nb >> 3, r = nb & 7;
  int xcd = bid & 7, idx = bid >> 3;
  return (xcd < r) ? (xcd*(q+1) + idx) : (r + xcd*q + idx);
}

// tanh-form GELU: v * sigmoid(2*0.79788456*(v + 0.044715 v^3)); |err| ~1e-3
__device__ __forceinline__ float gelu_f(float v){
  float y = 0.797884561f*(v + 0.044715f*v*v*v);
  float e = __expf(-2.f*y);
  return v * __builtin_amdgcn_rcpf(1.f + e);
}

// ---------------- weight fp32 -> bf16 ----------------
__global__ void k_f2bf(const float* __restrict__ in, bf16* __restrict__ out, int n){
  int i = blockIdx.x*256 + threadIdx.x;
  if (i < n) out[i] = f2bf(in[i]);
}

// ------- combined bias+mask table (f32): comb[cls(8)][head(12)][row 128][col 128] -------
__global__ void k_comb(const float* __restrict__ rpb, float* __restrict__ comb){
  int idx = blockIdx.x*256 + threadIdx.x;        // 96*128*128
  int col = idx & 127, row = (idx>>7)&127, clshead = idx>>14;
  int cls = clshead/12, head = clshead - cls*12;
  float v;
  if (row >= 98) v = 0.f;
  else if (col >= 98) v = -10000.f;
  else {
    int qd = row/49, qr = row%49, qh = qr/7, qw = qr%7;
    int kd = col/49, kr = col%49, kh = kr/7, kw = kr%7;
    int pbq = qd*169 + qh*13 + qw;
    int pbk = kd*169 + kh*13 + kw;
    int lq, lk;
    {
      int ld = (cls&4) ? (qd==0?1:2) : 0;
      int lh = (cls&2) ? (qh<4?1:2) : 0;
      int lw = (cls&1) ? (qw<4?1:2) : 0;
      lq = ld*9+lh*3+lw;
    }
    {
      int ld = (cls&4) ? (kd==0?1:2) : 0;
      int lh = (cls&2) ? (kh<4?1:2) : 0;
      int lw = (cls&1) ? (kw<4?1:2) : 0;
      lk = ld*9+lh*3+lw;
    }
    float bias = rpb[(pbq-pbk+253)*12 + head];
    v = bias + ((lq!=lk) ? -100.f : 0.f);
  }
  comb[idx] = v;
}

// ------- LN1 + cyclic shift + window partition (one wave per token) -------
__global__ __launch_bounds__(256)
void k_ln1(const float* __restrict__ x, const float* __restrict__ g,
           const float* __restrict__ b, bf16* __restrict__ xw, long tbase)
{
  int tl = blockIdx.x*4 + (threadIdx.x>>6);
  long t = tbase + tl;
  int lane = threadIdx.x & 63;
  int win = (int)(t / 98), n = (int)(t % 98);
  int batch = win>>8;
  int wq = win & 7, hq = (win>>3)&7, dq = (win>>6)&3;
  int dr = n/49, rem = n%49, hr = rem/7, wr = rem%7;
  int d = dq*2+dr, h = hq*7+hr, w = wq*7+wr;
  int sd = (d+1)&7;
  int sh = h+3; if (sh>=56) sh-=56;
  int sw = w+3; if (sw>=56) sw-=56;
  const float* row = x + ((size_t)(((batch*8+sd)*56+sh)*56+sw))*384;
  float v[6]; float s=0.f, ss=0.f;
  int c0 = lane*6;
  #pragma unroll
  for (int i=0;i<6;++i){ float f = row[c0+i]; v[i]=f; s+=f; ss+=f*f; }
  #pragma unroll
  for (int o=32;o>0;o>>=1){ s += __shfl_xor(s,o); ss += __shfl_xor(ss,o); }
  float mu = s*(1.f/384.f);
  float var = ss*(1.f/384.f) - mu*mu;
  float rstd = rsqrtf(var + 1e-5f);
  bf16* orow = xw + (size_t)tl*384;
  #pragma unroll
  for (int i=0;i<6;++i){ int c=c0+i; orow[c] = f2bf((v[i]-mu)*rstd*g[c] + b[c]); }
}

// ------- scatter (window reverse + roll back) + residual + LN2 -------
__global__ __launch_bounds__(256)
void k_scatter_ln2(const bf16* __restrict__ projout, const float* __restrict__ x,
                   const float* __restrict__ g, const float* __restrict__ b,
                   float* __restrict__ x2, bf16* __restrict__ ln2,
                   long tbase, long lnbase)
{
  int tl = blockIdx.x*4 + (threadIdx.x>>6);
  long t = tbase + tl;
  int lane = threadIdx.x & 63;
  int win = (int)(t/98), n = (int)(t%98);
  int batch = win>>8;
  int wq = win&7, hq=(win>>3)&7, dq=(win>>6)&3;
  int dr=n/49, rem=n%49, hr=rem/7, wr=rem%7;
  int d=dq*2+dr, h=hq*7+hr, w=wq*7+wr;
  int sd=(d+1)&7;
  int sh=h+3; if(sh>=56)sh-=56;
  int sw=w+3; if(sw>=56)sw-=56;
  size_t nat = (size_t)(sd*56+sh)*56 + sw;            // within batch [0,25088)
  size_t nrow = (size_t)batch*25088 + nat;            // global natural row
  const float* xrow = x + nrow*384;
  const bf16* prow = projout + (size_t)tl*384;
  float* x2row = x2 + nrow*384;
  bf16* lrow = ln2 + (nrow - (size_t)lnbase)*384;
  int c0 = lane*6;
  float v[6]; float s=0.f, ss=0.f;
  #pragma unroll
  for (int i=0;i<6;++i){
    float f = xrow[c0+i] + bf2f(prow[c0+i]);
    v[i]=f; s+=f; ss+=f*f;
    x2row[c0+i] = f;
  }
  #pragma unroll
  for (int o=32;o>0;o>>=1){ s+=__shfl_xor(s,o); ss+=__shfl_xor(ss,o); }
  float mu=s*(1.f/384.f), var=ss*(1.f/384.f)-mu*mu, rstd=rsqrtf(var+1e-5f);
  #pragma unroll
  for (int i=0;i<6;++i){ int c=c0+i; lrow[c]=f2bf((v[i]-mu)*rstd*g[c]+b[c]); }
}

// ------- bf16 MFMA GEMM, out[m,n] = sum_k A[m,k]*B[n,k] + bias[n] (both K-major) -------
// R7 pipeline (3-ring, depth-2, counted vmcnt, 1 barrier/iter) with UNROLL-BY-3:
// inner 3 steps unrolled so ring indices (rb=u, sb=(u+2)%3) are compile-time ->
// static LDS addresses (R9's VALU win) at ~6 iterations of code (no I$ blowup).
// Tail (last 3 steps) peeled with exact vmcnt ladder 4/4/0. KT must be %3==0.
// Chunk-XOR LDS swizzle (measured 0 conflicts).
// EPI: 0 = bias -> bf16; 1 = bias+GELU -> bf16; 2 = bias+resid -> f32; 3 = bias, scale cols<384 -> bf16
template<int EPI, int KT>
__global__ __launch_bounds__(256)
void k_gemm(const bf16* __restrict__ A, const bf16* __restrict__ B,
            const float* __restrict__ bias, const float* __restrict__ resid,
            void* __restrict__ outp, int N, int nx)
{
  constexpr int K = KT*32;
  static_assert(KT % 3 == 0, "KT must be divisible by 3");
  constexpr int G = KT/3;
  __shared__ __align__(16) bf16 As[3][128*32];
  __shared__ __align__(16) bf16 Bs[3][128*32];
  const int tid = threadIdx.x;
  const int wave = tid>>6, lane = tid&63;
  const int wg = xcd_swizzle(blockIdx.x, gridDim.x);
  const int tn = wg % nx, tm = wg / nx;
  const int wm = wave>>1, wn = wave&1;      // 2x2 waves -> 64x64 per wave
  const int fr = lane & 15, l4 = lane>>4;

  f32x4v acc[4][4];
  #pragma unroll
  for (int i=0;i<4;++i)
    #pragma unroll
    for (int j=0;j<4;++j)
      #pragma unroll
      for (int e=0;e<4;++e) acc[i][j][e] = 0.f;

  const int srow0 = lane>>2;
  // pre-swizzled global chunk: LDS[r][c] holds global[r][c ^ ((r>>1)&3)]
  const int scol_sw = (((lane&3) ^ ((lane>>3)&3)))*8;
  const bf16* ga0 = A + (size_t)(tm*128 +      wave*16 + srow0)*K + scol_sw;
  const bf16* ga1 = A + (size_t)(tm*128 + 64 + wave*16 + srow0)*K + scol_sw;
  const bf16* gb0 = B + (size_t)(tn*128 +      wave*16 + srow0)*K + scol_sw;
  const bf16* gb1 = B + (size_t)(tn*128 + 64 + wave*16 + srow0)*K + scol_sw;

  auto stage = [&](int buf, int koff){
    gload16(ga0 + koff, &As[buf][       wave*512]);
    gload16(ga1 + koff, &As[buf][2048 + wave*512]);
    gload16(gb0 + koff, &Bs[buf][       wave*512]);
    gload16(gb1 + koff, &Bs[buf][2048 + wave*512]);
  };

  stage(0, 0); stage(1, 32);      // depth-2 prefetch (8 loads in flight)

  // swizzled read chunk (lane-constant)
  const int fko_sw = ((l4 ^ ((fr>>1)&3)))*8;

  auto compute = [&](int u){       // u compile-time under unroll
    const bf16* Ab = As[u];
    const bf16* Bb = Bs[u];
    s16x8 af[4], bfr[4];
    #pragma unroll
    for (int i=0;i<4;++i){
      af[i]  = *(const s16x8*)&Ab[(wm*64 + i*16 + fr)*32 + fko_sw];
      bfr[i] = *(const s16x8*)&Bb[(wn*64 + i*16 + fr)*32 + fko_sw];
    }
    #pragma unroll
    for (int mi=0;mi<4;++mi)
      #pragma unroll
      for (int ni=0;ni<4;++ni)
        acc[mi][ni] = __builtin_amdgcn_mfma_f32_16x16x32_bf16(af[mi], bfr[ni], acc[mi][ni], 0,0,0);
  };

  int koff = 64;                    // element offset of tile kt+2 at loop head
  for (int g=0; g<G-1; ++g){
    #pragma unroll
    for (int u=0; u<3; ++u){
      asm volatile("s_waitcnt vmcnt(4) lgkmcnt(0)" ::: "memory");
      __builtin_amdgcn_s_barrier();
      stage((u+2)%3, koff + u*32);
      compute(u);
    }
    koff += 96;
  }
  // peeled final group (kt = KT-3, KT-2, KT-1)
  asm volatile("s_waitcnt vmcnt(4) lgkmcnt(0)" ::: "memory");
  __builtin_amdgcn_s_barrier();
  stage(2, koff);                  // tile KT-1
  compute(0);
  asm volatile("s_waitcnt vmcnt(4) lgkmcnt(0)" ::: "memory");
  __builtin_amdgcn_s_barrier();
  compute(1);
  asm volatile("s_waitcnt vmcnt(0) lgkmcnt(0)" ::: "memory");
  __builtin_amdgcn_s_barrier();
  compute(2);

  #pragma unroll
  for (int mi=0;mi<4;++mi){
    #pragma unroll
    for (int ni=0;ni<4;++ni){
      int col = tn*128 + wn*64 + ni*16 + fr;
      float bv = bias[col];
      int rowb = tm*128 + wm*64 + mi*16 + l4*4;
      #pragma unroll
      for (int r=0;r<4;++r){
        size_t idx = (size_t)(rowb+r)*N + col;
        float v = acc[mi][ni][r] + bv;
        if (EPI==0){
          ((bf16*)outp)[idx] = f2bf(v);
        } else if (EPI==1){
          ((bf16*)outp)[idx] = f2bf(gelu_f(v));
        } else if (EPI==3){
          if (col < 384) v *= 0.17677669529663687f;
          ((bf16*)outp)[idx] = f2bf(v);
        } else {
          ((float*)outp)[idx] = v + resid[idx];
        }
      }
    }
  }
}

// ------- MFMA windowed attention: 4 waves per block, one (win, head) per block -------
__global__ __launch_bounds__(256)
void k_attn(const bf16* __restrict__ qkv, const float* __restrict__ comb,
            bf16* __restrict__ outp)
{
  const int wg   = xcd_swizzle(blockIdx.x, gridDim.x);
  const int head = wg % 12;
  const int win  = wg / 12;
  const int tid  = threadIdx.x;
  const int wave = tid>>6;
  const int lane = tid&63;
  const int l15 = lane & 15, l4 = lane>>4;
  __shared__ __align__(16) bf16 Vt[32*136];       // V transposed [d][m], padded stride
  __shared__ __align__(16) bf16 P_buf[4][16*40];  // per-wave P tile, padded stride

  const int wq = win&7, hq=(win>>3)&7, dq=(win>>6)&3;
  const int cls = ((dq==3)?4:0) | ((hq==7)?2:0) | ((wq==7)?1:0);
  const float* combbase = comb + (size_t)(cls*12+head)*128*128;
  const bf16* qkvw_ = qkv + (size_t)win*98*1152;

  // cooperative V-transpose staging
  for (int i = tid; i < 512; i += 256){
    int m = i>>2, d0 = (i&3)*8;
    int mc = m>97 ? 97 : m;
    s16x8 v = *(const s16x8*)(qkvw_ + (size_t)mc*1152 + 768 + head*32 + d0);
    #pragma unroll
    for (int e=0;e<8;++e){ short sv = v[e]; Vt[(d0+e)*136 + m] = *(bf16*)&sv; }
  }
  // K fragments in registers
  s16x8 kb[8];
  #pragma unroll
  for (int j=0;j<8;++j){
    int tok = j*16 + l15; if (tok>97) tok = 97;
    kb[j] = *(const s16x8*)(qkvw_ + (size_t)tok*1152 + 384 + head*32 + l4*8);
  }
  __syncthreads();

  const int c0 = wave*32;          // this wave's 32 query rows
  bf16* Pw = P_buf[wave];
  #pragma unroll
  for (int mi=0;mi<2;++mi){
    int q = c0 + mi*16 + l15; if (q>97) q=97;
    s16x8 aq = *(const s16x8*)(qkvw_ + (size_t)q*1152 + head*32 + l4*8);
    f32x4v s[8];
    const float* cb = combbase + (size_t)(c0+mi*16+l4*4)*128 + l15;
    #pragma unroll
    for (int j=0;j<8;++j){
      f32x4v ci = { cb[j*16], cb[j*16+128], cb[j*16+256], cb[j*16+384] };
      s[j] = __builtin_amdgcn_mfma_f32_16x16x32_bf16(aq, kb[j], ci, 0,0,0);
    }
    float rinv[4];
    #pragma unroll
    for (int r=0;r<4;++r){
      float mx = s[0][r];
      #pragma unroll
      for (int j=1;j<8;++j) mx = fmaxf(mx, s[j][r]);
      mx = fmaxf(mx, __shfl_xor(mx,1));
      mx = fmaxf(mx, __shfl_xor(mx,2));
      mx = fmaxf(mx, __shfl_xor(mx,4));
      mx = fmaxf(mx, __shfl_xor(mx,8));
      float sum = 0.f;
      #pragma unroll
      for (int j=0;j<8;++j){ float e = __expf(s[j][r]-mx); s[j][r]=e; sum+=e; }
      sum += __shfl_xor(sum,1);
      sum += __shfl_xor(sum,2);
      sum += __shfl_xor(sum,4);
      sum += __shfl_xor(sum,8);
      rinv[r] = 1.f/sum;
    }
    f32x4v oacc[2] = {{0.f,0.f,0.f,0.f},{0.f,0.f,0.f,0.f}};
    #pragma unroll
    for (int ks=0; ks<4; ++ks){
      #pragma unroll
      for (int jj=0;jj<2;++jj)
        #pragma unroll
        for (int r=0;r<4;++r)
          Pw[(l4*4+r)*40 + jj*16 + l15] = f2bf(s[ks*2+jj][r]);
      s16x8 pa = *(const s16x8*)&Pw[l15*40 + l4*8];
      #pragma unroll
      for (int ni=0;ni<2;++ni){
        s16x8 vb = *(const s16x8*)&Vt[(ni*16+l15)*136 + ks*32 + l4*8];
        oacc[ni] = __builtin_amdgcn_mfma_f32_16x16x32_bf16(pa, vb, oacc[ni], 0,0,0);
      }
    }
    #pragma unroll
    for (int r=0;r<4;++r){
      int qo = c0 + mi*16 + l4*4 + r;
      if (qo < 98){
        bf16* orow = outp + ((size_t)win*98 + qo)*384 + head*32;
        #pragma unroll
        for (int ni=0;ni<2;++ni)
          orow[ni*16+l15] = f2bf(oacc[ni][r]*rinv[r]);
      }
    }
  }
}

extern "C" void kernel_launch(void* const* d_in, const int* in_sizes, int n_in,
                              void* d_out, int out_size, void* d_ws, size_t ws_size,
                              hipStream_t stream)
{
  const float* x     = (const float*)d_in[0];
  const float* n1g   = (const float*)d_in[1];
  const float* n1b   = (const float*)d_in[2];
  const float* qkvw  = (const float*)d_in[3];
  const float* qkvbv = (const float*)d_in[4];
  const float* rpb   = (const float*)d_in[5];
  const float* projw = (const float*)d_in[6];
  const float* projb = (const float*)d_in[7];
  const float* n2g   = (const float*)d_in[8];
  const float* n2b   = (const float*)d_in[9];
  const float* fc1w  = (const float*)d_in[10];
  const float* fc1b  = (const float*)d_in[11];
  const float* fc2w  = (const float*)d_in[12];
  const float* fc2b  = (const float*)d_in[13];
  float* out = (float*)d_out;

  char* ws = (char*)d_ws;
  size_t off = 0;
  auto alloc = [&](size_t bytes)->char*{
    char* p = ws + off; off += (bytes + 255) & ~(size_t)255; return p;
  };
  bf16*  wqkv  = (bf16*)alloc((size_t)1152*384*2);
  bf16*  wproj = (bf16*)alloc((size_t)384*384*2);
  bf16*  wfc1  = (bf16*)alloc((size_t)1536*384*2);
  bf16*  wfc2  = (bf16*)alloc((size_t)384*1536*2);
  float* comb  = (float*)alloc((size_t)96*128*128*4);

  k_f2bf<<<(1152*384+255)/256,256,0,stream>>>(qkvw, wqkv, 1152*384);
  k_f2bf<<<(384*384+255)/256,256,0,stream>>>(projw, wproj, 384*384);
  k_f2bf<<<(1536*384+255)/256,256,0,stream>>>(fc1w, wfc1, 1536*384);
  k_f2bf<<<(384*1536+255)/256,256,0,stream>>>(fc2w, wfc2, 384*1536);
  k_comb<<<6144,256,0,stream>>>(rpb, comb);

  const size_t fused_need = off + ((size_t)100352*384*2 + 255 & ~(size_t)255)
                                + ((size_t)100352*1536*2 + 255 & ~(size_t)255)
                                + ((size_t)100352*384*2 + 255 & ~(size_t)255);
  if (ws_size >= fused_need){
    // ---- all-batch fused pipeline (12 launches) ----
    bf16* xw   = (bf16*)alloc((size_t)100352*384*2);   // ln1 out; reused as proj out
    bf16* bufA = (bf16*)alloc((size_t)100352*1536*2);  // qkv out (1152 cols) / fc1 out
    bf16* ln2  = (bf16*)alloc((size_t)100352*384*2);
    bf16* attno = bufA + (size_t)100352*1152;          // tail of bufA during attention
    bf16* projo = xw;

    k_ln1<<<25088,256,0,stream>>>(x, n1g, n1b, xw, 0L);
    k_gemm<3,12><<<9*784,256,0,stream>>>(xw, wqkv, qkvbv, nullptr, bufA, 1152, 9);
    k_attn<<<12*1024,256,0,stream>>>(bufA, comb, attno);
    k_gemm<0,12><<<3*784,256,0,stream>>>(attno, wproj, projb, nullptr, projo, 384, 3);
    k_scatter_ln2<<<25088,256,0,stream>>>(projo, x, n2g, n2b, out, ln2, 0L, 0L);
    k_gemm<1,12><<<12*784,256,0,stream>>>(ln2, wfc1, fc1b, nullptr, bufA, 1536, 12);
    k_gemm<2,48><<<3*784,256,0,stream>>>(bufA, wfc2, fc2b, out, (void*)out, 384, 3);
  } else {
    // ---- per-batch fallback ----
    bf16* xw   = (bf16*)alloc((size_t)25088*384*2);
    bf16* bufA = (bf16*)alloc((size_t)25088*1536*2);
    bf16* ln2  = (bf16*)alloc((size_t)25088*384*2);
    bf16* attno = bufA + (size_t)25088*1152;
    bf16* projo = xw;
    for (int b=0; b<4; ++b){
      long tbase = (long)b*25088;
      k_ln1<<<6272,256,0,stream>>>(x, n1g, n1b, xw, tbase);
      k_gemm<3,12><<<9*196,256,0,stream>>>(xw, wqkv, qkvbv, nullptr, bufA, 1152, 9);
      k_attn<<<12*256,256,0,stream>>>(bufA, comb, attno);
      k_gemm<0,12><<<3*196,256,0,stream>>>(attno, wproj, projb, nullptr, projo, 384, 3);
      k_scatter_ln2<<<6272,256,0,stream>>>(projo, x, n2g, n2b, out, ln2, tbase, tbase);
      k_gemm<1,12><<<12*196,256,0,stream>>>(ln2, wfc1, fc1b, nullptr, bufA, 1536, 12);
      float* resid = out + (size_t)b*25088*384;
      k_gemm<2,48><<<3*196,256,0,stream>>>(bufA, wfc2, fc2b, resid, (void*)resid, 384, 3);
    }
  }
}

// Round 11
// 954.283 us; speedup vs baseline: 1.8114x; 1.0304x over previous
//
#include <hip/hip_runtime.h>
#include <hip/hip_bf16.h>
#include <cmath>

typedef __hip_bfloat16 bf16;
typedef __attribute__((ext_vector_type(8))) short s16x8;
typedef __attribute__((ext_vector_type(4))) float f32x4v;

__device__ __forceinline__ float bf2f(bf16 v){ return __bfloat162float(v); }
__device__ __forceinline__ bf16  f2bf(float v){ return __float2bfloat16(v); }

__device__ __forceinline__ void gload16(const void* g, void* l){
  __builtin_amdgcn_global_load_lds((const __attribute__((address_space(1))) void*)g,
                                   (__attribute__((address_space(3))) void*)l,
                                   16, 0, 0);
}

// bijective XCD-chunk swizzle (m204)
__device__ __forceinline__ int xcd_swizzle(int bid, int nb){
  int q = nb >> 3, r = nb & 7;
  int xcd = bid & 7, idx = bid >> 3;
  return (xcd < r) ? (xcd*(q+1) + idx) : (r + xcd*q + idx);
}

// tanh-form GELU: v * sigmoid(2*0.79788456*(v + 0.044715 v^3)); |err| ~1e-3
__device__ __forceinline__ float gelu_f(float v){
  float y = 0.797884561f*(v + 0.044715f*v*v*v);
  float e = __expf(-2.f*y);
  return v * __builtin_amdgcn_rcpf(1.f + e);
}

// ---------------- weight fp32 -> bf16 ----------------
__global__ void k_f2bf(const float* __restrict__ in, bf16* __restrict__ out, int n){
  int i = blockIdx.x*256 + threadIdx.x;
  if (i < n) out[i] = f2bf(in[i]);
}

// ------- combined bias+mask table (f32): comb[cls(8)][head(12)][row 128][col 128] -------
__global__ void k_comb(const float* __restrict__ rpb, float* __restrict__ comb){
  int idx = blockIdx.x*256 + threadIdx.x;        // 96*128*128
  int col = idx & 127, row = (idx>>7)&127, clshead = idx>>14;
  int cls = clshead/12, head = clshead - cls*12;
  float v;
  if (row >= 98) v = 0.f;
  else if (col >= 98) v = -10000.f;
  else {
    int qd = row/49, qr = row%49, qh = qr/7, qw = qr%7;
    int kd = col/49, kr = col%49, kh = kr/7, kw = kr%7;
    int pbq = qd*169 + qh*13 + qw;
    int pbk = kd*169 + kh*13 + kw;
    int lq, lk;
    {
      int ld = (cls&4) ? (qd==0?1:2) : 0;
      int lh = (cls&2) ? (qh<4?1:2) : 0;
      int lw = (cls&1) ? (qw<4?1:2) : 0;
      lq = ld*9+lh*3+lw;
    }
    {
      int ld = (cls&4) ? (kd==0?1:2) : 0;
      int lh = (cls&2) ? (kh<4?1:2) : 0;
      int lw = (cls&1) ? (kw<4?1:2) : 0;
      lk = ld*9+lh*3+lw;
    }
    float bias = rpb[(pbq-pbk+253)*12 + head];
    v = bias + ((lq!=lk) ? -100.f : 0.f);
  }
  comb[idx] = v;
}

// ------- LN1 + cyclic shift + window partition (one wave per token) -------
__global__ __launch_bounds__(256)
void k_ln1(const float* __restrict__ x, const float* __restrict__ g,
           const float* __restrict__ b, bf16* __restrict__ xw, long tbase)
{
  int tl = blockIdx.x*4 + (threadIdx.x>>6);
  long t = tbase + tl;
  int lane = threadIdx.x & 63;
  int win = (int)(t / 98), n = (int)(t % 98);
  int batch = win>>8;
  int wq = win & 7, hq = (win>>3)&7, dq = (win>>6)&3;
  int dr = n/49, rem = n%49, hr = rem/7, wr = rem%7;
  int d = dq*2+dr, h = hq*7+hr, w = wq*7+wr;
  int sd = (d+1)&7;
  int sh = h+3; if (sh>=56) sh-=56;
  int sw = w+3; if (sw>=56) sw-=56;
  const float* row = x + ((size_t)(((batch*8+sd)*56+sh)*56+sw))*384;
  float v[6]; float s=0.f, ss=0.f;
  int c0 = lane*6;
  #pragma unroll
  for (int i=0;i<6;++i){ float f = row[c0+i]; v[i]=f; s+=f; ss+=f*f; }
  #pragma unroll
  for (int o=32;o>0;o>>=1){ s += __shfl_xor(s,o); ss += __shfl_xor(ss,o); }
  float mu = s*(1.f/384.f);
  float var = ss*(1.f/384.f) - mu*mu;
  float rstd = rsqrtf(var + 1e-5f);
  bf16* orow = xw + (size_t)tl*384;
  #pragma unroll
  for (int i=0;i<6;++i){ int c=c0+i; orow[c] = f2bf((v[i]-mu)*rstd*g[c] + b[c]); }
}

// ------- scatter (window reverse + roll back) + residual + LN2 -------
__global__ __launch_bounds__(256)
void k_scatter_ln2(const bf16* __restrict__ projout, const float* __restrict__ x,
                   const float* __restrict__ g, const float* __restrict__ b,
                   float* __restrict__ x2, bf16* __restrict__ ln2,
                   long tbase, long lnbase)
{
  int tl = blockIdx.x*4 + (threadIdx.x>>6);
  long t = tbase + tl;
  int lane = threadIdx.x & 63;
  int win = (int)(t/98), n = (int)(t%98);
  int batch = win>>8;
  int wq = win&7, hq=(win>>3)&7, dq=(win>>6)&3;
  int dr=n/49, rem=n%49, hr=rem/7, wr=rem%7;
  int d=dq*2+dr, h=hq*7+hr, w=wq*7+wr;
  int sd=(d+1)&7;
  int sh=h+3; if(sh>=56)sh-=56;
  int sw=w+3; if(sw>=56)sw-=56;
  size_t nat = (size_t)(sd*56+sh)*56 + sw;            // within batch [0,25088)
  size_t nrow = (size_t)batch*25088 + nat;            // global natural row
  const float* xrow = x + nrow*384;
  const bf16* prow = projout + (size_t)tl*384;
  float* x2row = x2 + nrow*384;
  bf16* lrow = ln2 + (nrow - (size_t)lnbase)*384;
  int c0 = lane*6;
  float v[6]; float s=0.f, ss=0.f;
  #pragma unroll
  for (int i=0;i<6;++i){
    float f = xrow[c0+i] + bf2f(prow[c0+i]);
    v[i]=f; s+=f; ss+=f*f;
    x2row[c0+i] = f;
  }
  #pragma unroll
  for (int o=32;o>0;o>>=1){ s+=__shfl_xor(s,o); ss+=__shfl_xor(ss,o); }
  float mu=s*(1.f/384.f), var=ss*(1.f/384.f)-mu*mu, rstd=rsqrtf(var+1e-5f);
  #pragma unroll
  for (int i=0;i<6;++i){ int c=c0+i; lrow[c]=f2bf((v[i]-mu)*rstd*g[c]+b[c]); }
}

// ------- bf16 MFMA GEMM, out[m,n] = sum_k A[m,k]*B[n,k] + bias[n] (both K-major) -------
// Block tile 256x128 (M x N), 4 waves (2x2), wave tile 128x64: halves LDS bytes/FLOP
// vs 64x64 (the measured ~30%-MfmaUtil ceiling of R4..R10). Ring-2 LDS (49152 B,
// same footprint as R10 -> 2 blocks/CU guaranteed), depth-1 prefetch, m97-style
// drain: vmcnt(0)+barrier, stage next, ds_read+MFMA, barrier. #pragma unroll 2
// keeps buffer index compile-time. Chunk-XOR swizzle (measured 0 conflicts).
// __launch_bounds__(256,2) caps VGPR at 256 (acc 128 + 12x s16x8 frags ~ 200).
// EPI: 0 = bias -> bf16; 1 = bias+GELU -> bf16; 2 = bias+resid -> f32; 3 = bias, scale cols<384 -> bf16
template<int EPI, int KT>
__global__ __launch_bounds__(256, 2)
void k_gemm(const bf16* __restrict__ A, const bf16* __restrict__ B,
            const float* __restrict__ bias, const float* __restrict__ resid,
            void* __restrict__ outp, int N, int nx)
{
  constexpr int K = KT*32;
  __shared__ __align__(16) bf16 As[2][256*32];
  __shared__ __align__(16) bf16 Bs[2][128*32];
  const int tid = threadIdx.x;
  const int wave = tid>>6, lane = tid&63;
  const int wg = xcd_swizzle(blockIdx.x, gridDim.x);
  const int tn = wg % nx, tm = wg / nx;
  const int wm = wave>>1, wn = wave&1;      // wave tile 128x64 at (wm*128, wn*64)
  const int fr = lane & 15, l4 = lane>>4;

  f32x4v acc[8][4];
  #pragma unroll
  for (int i=0;i<8;++i)
    #pragma unroll
    for (int j=0;j<4;++j)
      #pragma unroll
      for (int e=0;e<4;++e) acc[i][j][e] = 0.f;

  const int srow0 = lane>>2;
  // pre-swizzled global chunk: LDS[r][c] holds global[r][c ^ ((r>>1)&3)]
  const int scol_sw = (((lane&3) ^ ((lane>>3)&3)))*8;
  const bf16* gA = A + ((size_t)tm*256 + wave*16 + srow0)*K + scol_sw;
  const bf16* gB = B + ((size_t)tn*128 + wave*16 + srow0)*K + scol_sw;

  auto stage = [&](int buf, int koff){
    #pragma unroll
    for (int j=0;j<4;++j)
      gload16(gA + (size_t)(64*j)*K + koff, &As[buf][j*2048 + wave*512]);
    #pragma unroll
    for (int j=0;j<2;++j)
      gload16(gB + (size_t)(64*j)*K + koff, &Bs[buf][j*2048 + wave*512]);
  };

  stage(0, 0);

  // swizzled read chunk (lane-constant)
  const int fko_sw = ((l4 ^ ((fr>>1)&3)))*8;

  #pragma unroll 2
  for (int kt=0; kt<KT; ++kt){
    asm volatile("s_waitcnt vmcnt(0) lgkmcnt(0)" ::: "memory");
    __builtin_amdgcn_s_barrier();
    if (kt+1 < KT) stage((kt+1)&1, (kt+1)*32);
    const bf16* Ab = As[kt&1];
    const bf16* Bb = Bs[kt&1];
    s16x8 af[8], bfr[4];
    #pragma unroll
    for (int i=0;i<4;++i)
      bfr[i] = *(const s16x8*)&Bb[(wn*64 + i*16 + fr)*32 + fko_sw];
    #pragma unroll
    for (int i=0;i<8;++i)
      af[i] = *(const s16x8*)&Ab[(wm*128 + i*16 + fr)*32 + fko_sw];
    #pragma unroll
    for (int mi=0;mi<8;++mi)
      #pragma unroll
      for (int ni=0;ni<4;++ni)
        acc[mi][ni] = __builtin_amdgcn_mfma_f32_16x16x32_bf16(af[mi], bfr[ni], acc[mi][ni], 0,0,0);
    __builtin_amdgcn_s_barrier();   // reads of buf kt retired before it is restaged
  }

  #pragma unroll
  for (int mi=0;mi<8;++mi){
    #pragma unroll
    for (int ni=0;ni<4;++ni){
      int col = tn*128 + wn*64 + ni*16 + fr;
      float bv = bias[col];
      int rowb = tm*256 + wm*128 + mi*16 + l4*4;
      #pragma unroll
      for (int r=0;r<4;++r){
        size_t idx = (size_t)(rowb+r)*N + col;
        float v = acc[mi][ni][r] + bv;
        if (EPI==0){
          ((bf16*)outp)[idx] = f2bf(v);
        } else if (EPI==1){
          ((bf16*)outp)[idx] = f2bf(gelu_f(v));
        } else if (EPI==3){
          if (col < 384) v *= 0.17677669529663687f;
          ((bf16*)outp)[idx] = f2bf(v);
        } else {
          ((float*)outp)[idx] = v + resid[idx];
        }
      }
    }
  }
}

// ------- MFMA windowed attention: 4 waves per block, one (win, head) per block -------
__global__ __launch_bounds__(256)
void k_attn(const bf16* __restrict__ qkv, const float* __restrict__ comb,
            bf16* __restrict__ outp)
{
  const int wg   = xcd_swizzle(blockIdx.x, gridDim.x);
  const int head = wg % 12;
  const int win  = wg / 12;
  const int tid  = threadIdx.x;
  const int wave = tid>>6;
  const int lane = tid&63;
  const int l15 = lane & 15, l4 = lane>>4;
  __shared__ __align__(16) bf16 Vt[32*136];       // V transposed [d][m], padded stride
  __shared__ __align__(16) bf16 P_buf[4][16*40];  // per-wave P tile, padded stride

  const int wq = win&7, hq=(win>>3)&7, dq=(win>>6)&3;
  const int cls = ((dq==3)?4:0) | ((hq==7)?2:0) | ((wq==7)?1:0);
  const float* combbase = comb + (size_t)(cls*12+head)*128*128;
  const bf16* qkvw_ = qkv + (size_t)win*98*1152;

  // cooperative V-transpose staging
  for (int i = tid; i < 512; i += 256){
    int m = i>>2, d0 = (i&3)*8;
    int mc = m>97 ? 97 : m;
    s16x8 v = *(const s16x8*)(qkvw_ + (size_t)mc*1152 + 768 + head*32 + d0);
    #pragma unroll
    for (int e=0;e<8;++e){ short sv = v[e]; Vt[(d0+e)*136 + m] = *(bf16*)&sv; }
  }
  // K fragments in registers
  s16x8 kb[8];
  #pragma unroll
  for (int j=0;j<8;++j){
    int tok = j*16 + l15; if (tok>97) tok = 97;
    kb[j] = *(const s16x8*)(qkvw_ + (size_t)tok*1152 + 384 + head*32 + l4*8);
  }
  __syncthreads();

  const int c0 = wave*32;          // this wave's 32 query rows
  bf16* Pw = P_buf[wave];
  #pragma unroll
  for (int mi=0;mi<2;++mi){
    int q = c0 + mi*16 + l15; if (q>97) q=97;
    s16x8 aq = *(const s16x8*)(qkvw_ + (size_t)q*1152 + head*32 + l4*8);
    f32x4v s[8];
    const float* cb = combbase + (size_t)(c0+mi*16+l4*4)*128 + l15;
    #pragma unroll
    for (int j=0;j<8;++j){
      f32x4v ci = { cb[j*16], cb[j*16+128], cb[j*16+256], cb[j*16+384] };
      s[j] = __builtin_amdgcn_mfma_f32_16x16x32_bf16(aq, kb[j], ci, 0,0,0);
    }
    float rinv[4];
    #pragma unroll
    for (int r=0;r<4;++r){
      float mx = s[0][r];
      #pragma unroll
      for (int j=1;j<8;++j) mx = fmaxf(mx, s[j][r]);
      mx = fmaxf(mx, __shfl_xor(mx,1));
      mx = fmaxf(mx, __shfl_xor(mx,2));
      mx = fmaxf(mx, __shfl_xor(mx,4));
      mx = fmaxf(mx, __shfl_xor(mx,8));
      float sum = 0.f;
      #pragma unroll
      for (int j=0;j<8;++j){ float e = __expf(s[j][r]-mx); s[j][r]=e; sum+=e; }
      sum += __shfl_xor(sum,1);
      sum += __shfl_xor(sum,2);
      sum += __shfl_xor(sum,4);
      sum += __shfl_xor(sum,8);
      rinv[r] = 1.f/sum;
    }
    f32x4v oacc[2] = {{0.f,0.f,0.f,0.f},{0.f,0.f,0.f,0.f}};
    #pragma unroll
    for (int ks=0; ks<4; ++ks){
      #pragma unroll
      for (int jj=0;jj<2;++jj)
        #pragma unroll
        for (int r=0;r<4;++r)
          Pw[(l4*4+r)*40 + jj*16 + l15] = f2bf(s[ks*2+jj][r]);
      s16x8 pa = *(const s16x8*)&Pw[l15*40 + l4*8];
      #pragma unroll
      for (int ni=0;ni<2;++ni){
        s16x8 vb = *(const s16x8*)&Vt[(ni*16+l15)*136 + ks*32 + l4*8];
        oacc[ni] = __builtin_amdgcn_mfma_f32_16x16x32_bf16(pa, vb, oacc[ni], 0,0,0);
      }
    }
    #pragma unroll
    for (int r=0;r<4;++r){
      int qo = c0 + mi*16 + l4*4 + r;
      if (qo < 98){
        bf16* orow = outp + ((size_t)win*98 + qo)*384 + head*32;
        #pragma unroll
        for (int ni=0;ni<2;++ni)
          orow[ni*16+l15] = f2bf(oacc[ni][r]*rinv[r]);
      }
    }
  }
}

extern "C" void kernel_launch(void* const* d_in, const int* in_sizes, int n_in,
                              void* d_out, int out_size, void* d_ws, size_t ws_size,
                              hipStream_t stream)
{
  const float* x     = (const float*)d_in[0];
  const float* n1g   = (const float*)d_in[1];
  const float* n1b   = (const float*)d_in[2];
  const float* qkvw  = (const float*)d_in[3];
  const float* qkvbv = (const float*)d_in[4];
  const float* rpb   = (const float*)d_in[5];
  const float* projw = (const float*)d_in[6];
  const float* projb = (const float*)d_in[7];
  const float* n2g   = (const float*)d_in[8];
  const float* n2b   = (const float*)d_in[9];
  const float* fc1w  = (const float*)d_in[10];
  const float* fc1b  = (const float*)d_in[11];
  const float* fc2w  = (const float*)d_in[12];
  const float* fc2b  = (const float*)d_in[13];
  float* out = (float*)d_out;

  char* ws = (char*)d_ws;
  size_t off = 0;
  auto alloc = [&](size_t bytes)->char*{
    char* p = ws + off; off += (bytes + 255) & ~(size_t)255; return p;
  };
  bf16*  wqkv  = (bf16*)alloc((size_t)1152*384*2);
  bf16*  wproj = (bf16*)alloc((size_t)384*384*2);
  bf16*  wfc1  = (bf16*)alloc((size_t)1536*384*2);
  bf16*  wfc2  = (bf16*)alloc((size_t)384*1536*2);
  float* comb  = (float*)alloc((size_t)96*128*128*4);

  k_f2bf<<<(1152*384+255)/256,256,0,stream>>>(qkvw, wqkv, 1152*384);
  k_f2bf<<<(384*384+255)/256,256,0,stream>>>(projw, wproj, 384*384);
  k_f2bf<<<(1536*384+255)/256,256,0,stream>>>(fc1w, wfc1, 1536*384);
  k_f2bf<<<(384*1536+255)/256,256,0,stream>>>(fc2w, wfc2, 384*1536);
  k_comb<<<6144,256,0,stream>>>(rpb, comb);

  const size_t fused_need = off + ((size_t)100352*384*2 + 255 & ~(size_t)255)
                                + ((size_t)100352*1536*2 + 255 & ~(size_t)255)
                                + ((size_t)100352*384*2 + 255 & ~(size_t)255);
  if (ws_size >= fused_need){
    // ---- all-batch fused pipeline (12 launches) ----
    bf16* xw   = (bf16*)alloc((size_t)100352*384*2);   // ln1 out; reused as proj out
    bf16* bufA = (bf16*)alloc((size_t)100352*1536*2);  // qkv out (1152 cols) / fc1 out
    bf16* ln2  = (bf16*)alloc((size_t)100352*384*2);
    bf16* attno = bufA + (size_t)100352*1152;          // tail of bufA during attention
    bf16* projo = xw;

    k_ln1<<<25088,256,0,stream>>>(x, n1g, n1b, xw, 0L);
    k_gemm<3,12><<<392*9,256,0,stream>>>(xw, wqkv, qkvbv, nullptr, bufA, 1152, 9);
    k_attn<<<12*1024,256,0,stream>>>(bufA, comb, attno);
    k_gemm<0,12><<<392*3,256,0,stream>>>(attno, wproj, projb, nullptr, projo, 384, 3);
    k_scatter_ln2<<<25088,256,0,stream>>>(projo, x, n2g, n2b, out, ln2, 0L, 0L);
    k_gemm<1,12><<<392*12,256,0,stream>>>(ln2, wfc1, fc1b, nullptr, bufA, 1536, 12);
    k_gemm<2,48><<<392*3,256,0,stream>>>(bufA, wfc2, fc2b, out, (void*)out, 384, 3);
  } else {
    // ---- per-batch fallback (M=25088 = 98*256) ----
    bf16* xw   = (bf16*)alloc((size_t)25088*384*2);
    bf16* bufA = (bf16*)alloc((size_t)25088*1536*2);
    bf16* ln2  = (bf16*)alloc((size_t)25088*384*2);
    bf16* attno = bufA + (size_t)25088*1152;
    bf16* projo = xw;
    for (int b=0; b<4; ++b){
      long tbase = (long)b*25088;
      k_ln1<<<6272,256,0,stream>>>(x, n1g, n1b, xw, tbase);
      k_gemm<3,12><<<98*9,256,0,stream>>>(xw, wqkv, qkvbv, nullptr, bufA, 1152, 9);
      k_attn<<<12*256,256,0,stream>>>(bufA, comb, attno);
      k_gemm<0,12><<<98*3,256,0,stream>>>(attno, wproj, projb, nullptr, projo, 384, 3);
      k_scatter_ln2<<<6272,256,0,stream>>>(projo, x, n2g, n2b, out, ln2, tbase, tbase);
      k_gemm<1,12><<<98*12,256,0,stream>>>(ln2, wfc1, fc1b, nullptr, bufA, 1536, 12);
      float* resid = out + (size_t)b*25088*384;
      k_gemm<2,48><<<98*3,256,0,stream>>>(bufA, wfc2, fc2b, resid, (void*)resid, 384, 3);
    }
  }
}